// Round 8
// baseline (289.768 us; speedup 1.0000x reference)
//
#include <hip/hip_runtime.h>
#include <hip/hip_fp16.h>
#include <math.h>

// ---- problem constants (match reference) ----
#define NNODES 100000
#define NEDGES 1600000
#define NLABEL 100000
#define DIM    64
#define ALPHA  0.25f            // 1/(NUM_LAYERS+1)
#define NB     782               // coarse buckets of 128 nodes (dst >> 7)
#define NBLKF  256               // blocks for count/fill1 (1024 threads each)

// ---- workspace layout (u32 words) ----
constexpr size_t OFF_DIS    = 0;         // f32 [100096]
constexpr size_t OFF_ROWPTR = 100096;    // int [100001] (pad to 200192)
constexpr size_t OFF_BCNT   = 200192;    // int [NB]
constexpr size_t OFF_BBASE  = 201088;    // int [NB+1]
constexpr size_t OFF_GCUR   = 201984;    // int [NB]
constexpr size_t OFF_CW     = 202880;    // int2[1600000] = 3200000 words
constexpr size_t OFF_EMB16  = 3402880;   // half[6400000] = 3200000 words
constexpr size_t OFF_X1     = 6602880;   // half[6400000] (aliased by tmp during fill)
constexpr size_t OFF_X2     = 9802880;   // half[6400000]
constexpr size_t OFF_OUTF16 = 13002880;  // half[6400000]
constexpr size_t OFF_PART   = 16202880;  // f32 [2048]

// convert fp32 embedding -> fp16
__global__ void k_cvt(const float* __restrict__ emb, __half* __restrict__ emb16) {
    int i = blockIdx.x * blockDim.x + threadIdx.x;   // one float4 / thread
    if (i < (NNODES * DIM) / 4) {
        float4 v = ((const float4*)emb)[i];
        float2 bits;
        ((__half2*)&bits)[0] = __float22half2_rn(make_float2(v.x, v.y));
        ((__half2*)&bits)[1] = __float22half2_rn(make_float2(v.z, v.w));
        ((float2*)emb16)[i] = bits;
    }
}

// coarse bucket counts: per-block LDS hist, one global atomic per (block,bucket)
__global__ __launch_bounds__(1024) void k_count(
    const int* __restrict__ ei, int* __restrict__ bcnt) {
    __shared__ int hist[NB];
    int tid = threadIdx.x;
    const int chunk = (((NEDGES + NBLKF - 1) / NBLKF) + 3) & ~3;   // 6252 (x4)
    int e0 = blockIdx.x * chunk;
    int e1 = min(e0 + chunk, NEDGES);
    for (int i = tid; i < NB; i += 1024) hist[i] = 0;
    __syncthreads();
    const int* dsts = ei + NEDGES;
    for (int e = e0 + tid * 4; e + 3 < e1; e += 4096) {
        int4 d = *(const int4*)(dsts + e);
        atomicAdd(&hist[d.x >> 7], 1);
        atomicAdd(&hist[d.y >> 7], 1);
        atomicAdd(&hist[d.z >> 7], 1);
        atomicAdd(&hist[d.w >> 7], 1);
    }
    __syncthreads();
    for (int b = tid; b < NB; b += 1024)
        if (hist[b]) atomicAdd(&bcnt[b], hist[b]);
}

// exclusive scan of bucket counts -> bucket bases; init fill cursors
__global__ __launch_bounds__(1024) void k_bscan(
    const int* __restrict__ bcnt, int* __restrict__ bbase, int* __restrict__ gcur) {
    __shared__ int s[1024];
    int tid = threadIdx.x;
    int v = (tid < NB) ? bcnt[tid] : 0;
    s[tid] = v;
    __syncthreads();
    for (int off = 1; off < 1024; off <<= 1) {
        int t = s[tid];
        if (tid >= off) t += s[tid - off];
        __syncthreads();
        s[tid] = t;
        __syncthreads();
    }
    if (tid < NB) {
        int base = s[tid] - v;
        bbase[tid] = base;
        gcur[tid] = base;
    }
    if (tid == NB) bbase[NB] = NEDGES;
}

// fill pass 1: partition edges into NB coarse buckets (128 dst-nodes each)
__global__ __launch_bounds__(1024) void k_fill1(
    const int* __restrict__ ei, int* __restrict__ gcursor,
    int2* __restrict__ tmp) {
    __shared__ int hist[NB];
    __shared__ int base[NB];
    int tid = threadIdx.x;
    const int chunk = (((NEDGES + NBLKF - 1) / NBLKF) + 3) & ~3;   // 6252 (x4)
    int e0 = blockIdx.x * chunk;
    int e1 = min(e0 + chunk, NEDGES);
    for (int i = tid; i < NB; i += 1024) hist[i] = 0;
    __syncthreads();
    const int* srcs = ei;
    const int* dsts = ei + NEDGES;
    for (int e = e0 + tid * 4; e + 3 < e1; e += 4096) {
        int4 d = *(const int4*)(dsts + e);
        atomicAdd(&hist[d.x >> 7], 1);
        atomicAdd(&hist[d.y >> 7], 1);
        atomicAdd(&hist[d.z >> 7], 1);
        atomicAdd(&hist[d.w >> 7], 1);
    }
    __syncthreads();
    for (int b = tid; b < NB; b += 1024) {
        int c = hist[b];
        base[b] = c ? atomicAdd(&gcursor[b], c) : 0;
        hist[b] = 0;
    }
    __syncthreads();
    for (int e = e0 + tid * 4; e + 3 < e1; e += 4096) {
        int4 s = *(const int4*)(srcs + e);
        int4 d = *(const int4*)(dsts + e);
        int b0 = d.x >> 7, b1 = d.y >> 7, b2 = d.z >> 7, b3 = d.w >> 7;
        int l0 = atomicAdd(&hist[b0], 1);
        int l1 = atomicAdd(&hist[b1], 1);
        int l2 = atomicAdd(&hist[b2], 1);
        int l3 = atomicAdd(&hist[b3], 1);
        int2 v;
        v.x = s.x; v.y = d.x; tmp[base[b0] + l0] = v;
        v.x = s.y; v.y = d.y; tmp[base[b1] + l1] = v;
        v.x = s.z; v.y = d.z; tmp[base[b2] + l2] = v;
        v.x = s.w; v.y = d.w; tmp[base[b3] + l3] = v;
    }
}

// fill pass 2a: per bucket, per-node degree in LDS -> dis + rowptr (coalesced)
__global__ __launch_bounds__(256) void k_fill2a(
    const int* __restrict__ bbase, const int2* __restrict__ tmp,
    float* __restrict__ dis, int* __restrict__ rowptr) {
    __shared__ int dcnt[128];
    __shared__ int sc[128];
    int b = blockIdx.x;
    int tid = threadIdx.x;
    int n0 = b << 7;
    int s0 = bbase[b];
    int n = bbase[b + 1] - s0;
    if (tid < 128) dcnt[tid] = 0;
    __syncthreads();
    for (int i = tid; i < n; i += 256)
        atomicAdd(&dcnt[tmp[s0 + i].y & 127], 1);
    __syncthreads();
    int node = n0 + tid;
    if (tid < 128) {
        int d = dcnt[tid];
        if (node < NNODES) dis[node] = d ? rsqrtf((float)d) : 0.0f;
        sc[tid] = d;
    }
    __syncthreads();
    for (int off = 1; off < 128; off <<= 1) {
        int t = 0;
        if (tid < 128) {
            t = sc[tid];
            if (tid >= off) t += sc[tid - off];
        }
        __syncthreads();
        if (tid < 128) sc[tid] = t;
        __syncthreads();
    }
    if (tid < 128 && node < NNODES) rowptr[node] = s0 + sc[tid] - dcnt[tid];
    if (b == 0 && tid == 0) rowptr[NNODES] = NEDGES;
}

// fill pass 2b: per bucket, build CSR segment in LDS, SORT each node's edges
// by src (ascending) so k_prop's gather sweeps the feature table low->high,
// attach weight, stream out coalesced.
__global__ __launch_bounds__(256) void k_fill2b(
    const int* __restrict__ bbase, const int* __restrict__ rowptr,
    const float* __restrict__ dis, const int2* __restrict__ tmp,
    int2* __restrict__ cw) {
    __shared__ int2 seg[4096];
    __shared__ int cur[128];
    int b = blockIdx.x;
    int tid = threadIdx.x;
    int n0 = b << 7;
    int s0 = bbase[b];
    int n = bbase[b + 1] - s0;
    if (tid < 128) {
        int node = n0 + tid;
        cur[tid] = (node < NNODES) ? rowptr[node] - s0 : n;
    }
    __syncthreads();
    for (int i = tid; i < n; i += 256) {
        int2 e = tmp[s0 + i];
        int ln = e.y & 127;
        int p = atomicAdd(&cur[ln], 1);
        if (p < 4096) {
            int2 v; v.x = e.x; v.y = __float_as_int(dis[e.x]);
            seg[p] = v;
        }
    }
    __syncthreads();
    // per-node insertion sort by src (threads 0..127, disjoint spans)
    if (tid < 128) {
        int node = n0 + tid;
        int st = (node < NNODES) ? rowptr[node] - s0 : n;
        int en = cur[tid];
        for (int i = st + 1; i < en; ++i) {
            int2 key = seg[i];
            int j = i - 1;
            while (j >= st && seg[j].x > key.x) {
                seg[j + 1] = seg[j];
                --j;
            }
            seg[j + 1] = key;
        }
    }
    __syncthreads();
    for (int i = tid; i < n; i += 256) cw[s0 + i] = seg[i];
}

// one wave per node; 4 edge-groups x 16 lanes; each lane owns 4 dims (8 B fp16).
// 4-deep edge pipeline per group; edges are src-sorted so the wave's gathers
// sweep the table in ascending order. MODE 0/1: dst = x_next. MODE 2: fused out.
template <int MODE>
__global__ __launch_bounds__(256) void k_prop(
    const int* __restrict__ rowptr, const int2* __restrict__ cw,
    const float* __restrict__ dis, const __half* __restrict__ xin,
    __half* __restrict__ dst, const __half* __restrict__ emb16,
    const __half* __restrict__ x1, const __half* __restrict__ x2) {
    int gt = blockIdx.x * 256 + threadIdx.x;
    int node = gt >> 6;
    if (node >= NNODES) return;
    int lane = threadIdx.x & 63;
    int g = lane >> 4;     // edge group 0..3
    int c = lane & 15;     // 4-dim chunk within row
    int r0 = __builtin_amdgcn_readfirstlane(rowptr[node]);
    int r1 = __builtin_amdgcn_readfirstlane(rowptr[node + 1]);
    float4 acc0 = {0.f, 0.f, 0.f, 0.f}, acc1 = {0.f, 0.f, 0.f, 0.f};
    float4 acc2 = {0.f, 0.f, 0.f, 0.f}, acc3 = {0.f, 0.f, 0.f, 0.f};
    int j = r0 + g;
    for (; j + 12 < r1; j += 16) {         // 4 edges per group in flight
        int2 e0 = cw[j];
        int2 e1 = cw[j + 4];
        int2 e2 = cw[j + 8];
        int2 e3 = cw[j + 12];
        float2 r0v = *(const float2*)(xin + (size_t)e0.x * DIM + c * 4);
        float2 r1v = *(const float2*)(xin + (size_t)e1.x * DIM + c * 4);
        float2 r2v = *(const float2*)(xin + (size_t)e2.x * DIM + c * 4);
        float2 r3v = *(const float2*)(xin + (size_t)e3.x * DIM + c * 4);
        float w0 = __int_as_float(e0.y), w1 = __int_as_float(e1.y);
        float w2 = __int_as_float(e2.y), w3 = __int_as_float(e3.y);
        float2 f0a = __half22float2(((__half2*)&r0v)[0]);
        float2 f0b = __half22float2(((__half2*)&r0v)[1]);
        float2 f1a = __half22float2(((__half2*)&r1v)[0]);
        float2 f1b = __half22float2(((__half2*)&r1v)[1]);
        float2 f2a = __half22float2(((__half2*)&r2v)[0]);
        float2 f2b = __half22float2(((__half2*)&r2v)[1]);
        float2 f3a = __half22float2(((__half2*)&r3v)[0]);
        float2 f3b = __half22float2(((__half2*)&r3v)[1]);
        acc0.x += w0 * f0a.x; acc0.y += w0 * f0a.y;
        acc0.z += w0 * f0b.x; acc0.w += w0 * f0b.y;
        acc1.x += w1 * f1a.x; acc1.y += w1 * f1a.y;
        acc1.z += w1 * f1b.x; acc1.w += w1 * f1b.y;
        acc2.x += w2 * f2a.x; acc2.y += w2 * f2a.y;
        acc2.z += w2 * f2b.x; acc2.w += w2 * f2b.y;
        acc3.x += w3 * f3a.x; acc3.y += w3 * f3a.y;
        acc3.z += w3 * f3b.x; acc3.w += w3 * f3b.y;
    }
    for (; j + 4 < r1; j += 8) {           // 2 edges
        int2 e0 = cw[j];
        int2 e1 = cw[j + 4];
        float2 r0v = *(const float2*)(xin + (size_t)e0.x * DIM + c * 4);
        float2 r1v = *(const float2*)(xin + (size_t)e1.x * DIM + c * 4);
        float w0 = __int_as_float(e0.y), w1 = __int_as_float(e1.y);
        float2 f0a = __half22float2(((__half2*)&r0v)[0]);
        float2 f0b = __half22float2(((__half2*)&r0v)[1]);
        float2 f1a = __half22float2(((__half2*)&r1v)[0]);
        float2 f1b = __half22float2(((__half2*)&r1v)[1]);
        acc0.x += w0 * f0a.x; acc0.y += w0 * f0a.y;
        acc0.z += w0 * f0b.x; acc0.w += w0 * f0b.y;
        acc1.x += w1 * f1a.x; acc1.y += w1 * f1a.y;
        acc1.z += w1 * f1b.x; acc1.w += w1 * f1b.y;
    }
    for (; j < r1; j += 4) {               // 1 edge
        int2 e = cw[j];
        float2 rv = *(const float2*)(xin + (size_t)e.x * DIM + c * 4);
        float w = __int_as_float(e.y);
        float2 f0 = __half22float2(((__half2*)&rv)[0]);
        float2 f1 = __half22float2(((__half2*)&rv)[1]);
        acc0.x += w * f0.x; acc0.y += w * f0.y;
        acc0.z += w * f1.x; acc0.w += w * f1.y;
    }
    acc0.x += acc1.x; acc0.y += acc1.y; acc0.z += acc1.z; acc0.w += acc1.w;
    acc2.x += acc3.x; acc2.y += acc3.y; acc2.z += acc3.z; acc2.w += acc3.w;
    acc0.x += acc2.x; acc0.y += acc2.y; acc0.z += acc2.z; acc0.w += acc2.w;
    acc0.x += __shfl_xor(acc0.x, 16); acc0.y += __shfl_xor(acc0.y, 16);
    acc0.z += __shfl_xor(acc0.z, 16); acc0.w += __shfl_xor(acc0.w, 16);
    acc0.x += __shfl_xor(acc0.x, 32); acc0.y += __shfl_xor(acc0.y, 32);
    acc0.z += __shfl_xor(acc0.z, 32); acc0.w += __shfl_xor(acc0.w, 32);
    if (lane < 16) {
        float dn = dis[node];
        float yx = dn * acc0.x, yy = dn * acc0.y;
        float yz = dn * acc0.z, yw = dn * acc0.w;
        size_t idx = (size_t)node * DIM + c * 4;
        if (MODE == 2) {
            float2 eb = *(const float2*)(emb16 + idx);
            float2 ab = *(const float2*)(x1 + idx);
            float2 bb = *(const float2*)(x2 + idx);
            float2 e0 = __half22float2(((__half2*)&eb)[0]);
            float2 e1 = __half22float2(((__half2*)&eb)[1]);
            float2 a0 = __half22float2(((__half2*)&ab)[0]);
            float2 a1 = __half22float2(((__half2*)&ab)[1]);
            float2 b0 = __half22float2(((__half2*)&bb)[0]);
            float2 b1 = __half22float2(((__half2*)&bb)[1]);
            yx = ALPHA * (e0.x + a0.x + b0.x + yx);
            yy = ALPHA * (e0.y + a0.y + b0.y + yy);
            yz = ALPHA * (e1.x + a1.x + b1.x + yz);
            yw = ALPHA * (e1.y + a1.y + b1.y + yw);
        }
        float2 bits;
        ((__half2*)&bits)[0] = __float22half2_rn(make_float2(yx, yy));
        ((__half2*)&bits)[1] = __float22half2_rn(make_float2(yz, yw));
        *(float2*)(dst + idx) = bits;
    }
}

// LDS-tiled MLP GEMM over fp16 outf: 64 labels/block, xs k-major fp32 in LDS.
__global__ __launch_bounds__(256) void k_mlp(
    const __half* __restrict__ outf, const int* __restrict__ eli,
    const float* __restrict__ lbl, const float* __restrict__ W1,
    const float* __restrict__ b1, const float* __restrict__ W2,
    const float* __restrict__ b2, float* __restrict__ pred,
    float* __restrict__ partial) {
    __shared__ float xs[128][68];
    __shared__ float w1s[128 * 64];
    __shared__ float ws[4];
    int tid = threadIdx.x;
    int lb = blockIdx.x * 64;

    {
        const float4* src = (const float4*)W1;
        float4* dst = (float4*)w1s;
        for (int i = tid; i < 2048; i += 256) dst[i] = src[i];
    }
    {
        int lab = tid >> 2, q = tid & 3;
        int l = lb + lab;
        int li = (l < NLABEL) ? l : (NLABEL - 1);
        int s = eli[li];
        int t = eli[NLABEL + li];
        const __half* srow = outf + (size_t)s * DIM;
        const __half* trow = outf + (size_t)t * DIM;
#pragma unroll
        for (int i = 0; i < 4; ++i) {
            int cc = q + 4 * i;           // 16B chunk 0..15 of the 256B concat row
            const __half* row = (cc < 8) ? srow + cc * 8 : trow + (cc - 8) * 8;
            float4 raw = *(const float4*)row;   // 8 halfs
            __half2* hp = (__half2*)&raw;
            int k = 8 * cc;
            float2 f;
            f = __half22float2(hp[0]); xs[k + 0][lab] = f.x; xs[k + 1][lab] = f.y;
            f = __half22float2(hp[1]); xs[k + 2][lab] = f.x; xs[k + 3][lab] = f.y;
            f = __half22float2(hp[2]); xs[k + 4][lab] = f.x; xs[k + 5][lab] = f.y;
            f = __half22float2(hp[3]); xs[k + 6][lab] = f.x; xs[k + 7][lab] = f.y;
        }
    }
    __syncthreads();

    int jcol = tid & 15;
    int lrow = tid >> 4;
    float acc[4][4];
#pragma unroll
    for (int a = 0; a < 4; ++a)
#pragma unroll
        for (int b = 0; b < 4; ++b) acc[a][b] = 0.f;

#pragma unroll 4
    for (int k = 0; k < 128; ++k) {
        float4 xv = *(const float4*)(&xs[k][4 * lrow]);
        float4 wv = *(const float4*)(&w1s[k * 64 + 4 * jcol]);
        acc[0][0] += xv.x * wv.x; acc[0][1] += xv.x * wv.y;
        acc[0][2] += xv.x * wv.z; acc[0][3] += xv.x * wv.w;
        acc[1][0] += xv.y * wv.x; acc[1][1] += xv.y * wv.y;
        acc[1][2] += xv.y * wv.z; acc[1][3] += xv.y * wv.w;
        acc[2][0] += xv.z * wv.x; acc[2][1] += xv.z * wv.y;
        acc[2][2] += xv.z * wv.z; acc[2][3] += xv.z * wv.w;
        acc[3][0] += xv.w * wv.x; acc[3][1] += xv.w * wv.y;
        acc[3][2] += xv.w * wv.z; acc[3][3] += xv.w * wv.w;
    }

    float4 b1v = *(const float4*)(b1 + 4 * jcol);
    float4 w2v = *(const float4*)(W2 + 4 * jcol);
    float p[4];
#pragma unroll
    for (int a = 0; a < 4; ++a) {
        p[a] = fmaxf(acc[a][0] + b1v.x, 0.f) * w2v.x
             + fmaxf(acc[a][1] + b1v.y, 0.f) * w2v.y
             + fmaxf(acc[a][2] + b1v.z, 0.f) * w2v.z
             + fmaxf(acc[a][3] + b1v.w, 0.f) * w2v.w;
    }
#pragma unroll
    for (int off = 1; off <= 8; off <<= 1) {
#pragma unroll
        for (int a = 0; a < 4; ++a) p[a] += __shfl_xor(p[a], off);
    }
    float lsum = 0.f;
    if (jcol == 0) {
        float b2v = b2[0];
#pragma unroll
        for (int a = 0; a < 4; ++a) {
            int l = lb + 4 * lrow + a;
            if (l < NLABEL) {
                float predv = p[a] + b2v;
                pred[l] = predv;
                float d = predv - lbl[l];
                lsum += d * d;
            }
        }
    }
    lsum += __shfl_xor(lsum, 16);
    lsum += __shfl_xor(lsum, 32);
    if ((tid & 63) == 0) ws[tid >> 6] = lsum;
    __syncthreads();
    if (tid == 0) partial[blockIdx.x] = (ws[0] + ws[1]) + (ws[2] + ws[3]);
}

__global__ void k_loss(const float* __restrict__ partial, float* __restrict__ lossout,
                       int n) {
    __shared__ float s[512];
    int tid = threadIdx.x;
    float v = 0.f;
    for (int i = tid; i < n; i += 512) v += partial[i];
    s[tid] = v;
    __syncthreads();
    for (int off = 256; off >= 1; off >>= 1) {
        if (tid < off) s[tid] += s[tid + off];
        __syncthreads();
    }
    if (tid == 0) lossout[0] = s[0] / (float)NLABEL;
}

extern "C" void kernel_launch(void* const* d_in, const int* in_sizes, int n_in,
                              void* d_out, int out_size, void* d_ws, size_t ws_size,
                              hipStream_t stream) {
    const int*   ei  = (const int*)d_in[0];
    const int*   eli = (const int*)d_in[1];
    const float* lbl = (const float*)d_in[2];
    const float* emb = (const float*)d_in[3];
    const float* W1  = (const float*)d_in[4];
    const float* b1  = (const float*)d_in[5];
    const float* W2  = (const float*)d_in[6];
    const float* b2  = (const float*)d_in[7];
    float* outp = (float*)d_out;               // pred[100000] ++ loss[1]

    char* wsb = (char*)d_ws;
    float*  dis    = (float*)wsb + OFF_DIS;
    int*    rowptr = (int*)wsb + OFF_ROWPTR;
    int*    bcnt   = (int*)wsb + OFF_BCNT;
    int*    bbase  = (int*)wsb + OFF_BBASE;
    int*    gcur   = (int*)wsb + OFF_GCUR;
    int2*   cw     = (int2*)((int*)wsb + OFF_CW);
    __half* emb16  = (__half*)((int*)wsb + OFF_EMB16);
    __half* x1     = (__half*)((int*)wsb + OFF_X1);
    __half* x2     = (__half*)((int*)wsb + OFF_X2);
    __half* outf   = (__half*)((int*)wsb + OFF_OUTF16);
    float*  part   = (float*)wsb + OFF_PART;
    int2*   tmp    = (int2*)x1;                // alias: free until k_prop<0>

    const int T = 256;
    hipMemsetAsync(bcnt, 0, NB * sizeof(int), stream);
    hipLaunchKernelGGL(k_cvt, dim3((NNODES * DIM / 4 + T - 1) / T), dim3(T), 0, stream, emb, emb16);
    hipLaunchKernelGGL(k_count, dim3(NBLKF), dim3(1024), 0, stream, ei, bcnt);
    hipLaunchKernelGGL(k_bscan, dim3(1), dim3(1024), 0, stream, bcnt, bbase, gcur);
    hipLaunchKernelGGL(k_fill1, dim3(NBLKF), dim3(1024), 0, stream, ei, gcur, tmp);
    hipLaunchKernelGGL(k_fill2a, dim3(NB), dim3(T), 0, stream, bbase, tmp, dis, rowptr);
    hipLaunchKernelGGL(k_fill2b, dim3(NB), dim3(T), 0, stream, bbase, rowptr, dis, tmp, cw);

    // x1 = P(emb); x2 = P(x1); outf = ALPHA*(emb + x1 + x2 + P(x2))   [all fp16]
    dim3 pgrid((NNODES * 64) / T);
    hipLaunchKernelGGL((k_prop<0>), pgrid, dim3(T), 0, stream, rowptr, cw, dis, emb16, x1,   nullptr, nullptr, nullptr);
    hipLaunchKernelGGL((k_prop<1>), pgrid, dim3(T), 0, stream, rowptr, cw, dis, x1,    x2,   nullptr, nullptr, nullptr);
    hipLaunchKernelGGL((k_prop<2>), pgrid, dim3(T), 0, stream, rowptr, cw, dis, x2,    outf, emb16, x1, x2);

    const int MLPB = (NLABEL + 63) / 64;   // 1563
    hipLaunchKernelGGL(k_mlp, dim3(MLPB), dim3(T), 0, stream, outf, eli, lbl, W1, b1, W2, b2, outp, part);
    hipLaunchKernelGGL(k_loss, dim3(1), dim3(512), 0, stream, part, outp + NLABEL, MLPB);
}

// Round 9
// 224.622 us; speedup vs baseline: 1.2900x; 1.2900x over previous
//
#include <hip/hip_runtime.h>
#include <hip/hip_fp16.h>
#include <math.h>

// ---- problem constants (match reference) ----
#define NNODES 100000
#define NEDGES 1600000
#define NLABEL 100000
#define DIM    64
#define ALPHA  0.25f            // 1/(NUM_LAYERS+1)
#define NB     782               // coarse buckets of 128 nodes (dst >> 7)
#define NBLKF  256               // blocks for fill1 (1024 threads each)
#define BCAP   4096              // per-bucket tmp capacity (mean 2046, sigma 45)

// ---- workspace layout (u32 words) ----
constexpr size_t OFF_DIS    = 0;         // f32 [100096]
constexpr size_t OFF_ROWPTR = 100096;    // int [100001] (pad to 200192)
constexpr size_t OFF_BBASE  = 200192;    // int [NB+1]
constexpr size_t OFF_GCUR   = 201088;    // int [NB]
constexpr size_t OFF_CW     = 202880;    // int [1600000] (src only)
constexpr size_t OFF_EMB16  = 3402880;   // half[6400000] = 3200000 words
constexpr size_t OFF_X1     = 6602880;   // half[6400000] (aliased by tmp during fill)
constexpr size_t OFF_X2     = 9802880;   // half[6400000] (tmp spills 3072 words in)
constexpr size_t OFF_OUTF16 = 13002880;  // half[6400000]
constexpr size_t OFF_PART   = 16202880;  // f32 [2048]

// convert fp32 embedding -> fp16
__global__ void k_cvt(const float* __restrict__ emb, __half* __restrict__ emb16) {
    int i = blockIdx.x * blockDim.x + threadIdx.x;   // one float4 / thread
    if (i < (NNODES * DIM) / 4) {
        float4 v = ((const float4*)emb)[i];
        float2 bits;
        ((__half2*)&bits)[0] = __float22half2_rn(make_float2(v.x, v.y));
        ((__half2*)&bits)[1] = __float22half2_rn(make_float2(v.z, v.w));
        ((float2*)emb16)[i] = bits;
    }
}

// single-pass binning: per-block LDS hist -> one global reserve per bucket ->
// packed 4B records (src<<7 | dst&127) into fixed-capacity bucket regions.
// gcur must be zeroed before; afterwards gcur[b] = bucket count.
__global__ __launch_bounds__(1024) void k_fill1(
    const int* __restrict__ ei, int* __restrict__ gcur,
    int* __restrict__ tmp) {
    __shared__ int hist[NB];
    __shared__ int base[NB];
    int tid = threadIdx.x;
    const int chunk = (((NEDGES + NBLKF - 1) / NBLKF) + 3) & ~3;   // 6252 (x4)
    int e0 = blockIdx.x * chunk;
    int e1 = min(e0 + chunk, NEDGES);
    for (int i = tid; i < NB; i += 1024) hist[i] = 0;
    __syncthreads();
    const int* srcs = ei;
    const int* dsts = ei + NEDGES;
    for (int e = e0 + tid * 4; e + 3 < e1; e += 4096) {
        int4 d = *(const int4*)(dsts + e);
        atomicAdd(&hist[d.x >> 7], 1);
        atomicAdd(&hist[d.y >> 7], 1);
        atomicAdd(&hist[d.z >> 7], 1);
        atomicAdd(&hist[d.w >> 7], 1);
    }
    __syncthreads();
    for (int b = tid; b < NB; b += 1024) {
        int c = hist[b];
        base[b] = c ? atomicAdd(&gcur[b], c) : 0;
        hist[b] = 0;
    }
    __syncthreads();
    for (int e = e0 + tid * 4; e + 3 < e1; e += 4096) {
        int4 s = *(const int4*)(srcs + e);
        int4 d = *(const int4*)(dsts + e);
        int b0 = d.x >> 7, b1 = d.y >> 7, b2 = d.z >> 7, b3 = d.w >> 7;
        int l0 = atomicAdd(&hist[b0], 1);
        int l1 = atomicAdd(&hist[b1], 1);
        int l2 = atomicAdd(&hist[b2], 1);
        int l3 = atomicAdd(&hist[b3], 1);
        int p0 = b0 * BCAP + min(base[b0] + l0, BCAP - 1);
        int p1 = b1 * BCAP + min(base[b1] + l1, BCAP - 1);
        int p2 = b2 * BCAP + min(base[b2] + l2, BCAP - 1);
        int p3 = b3 * BCAP + min(base[b3] + l3, BCAP - 1);
        tmp[p0] = (s.x << 7) | (d.x & 127);
        tmp[p1] = (s.y << 7) | (d.y & 127);
        tmp[p2] = (s.z << 7) | (d.z & 127);
        tmp[p3] = (s.w << 7) | (d.w & 127);
    }
}

// exclusive scan of bucket counts (in gcur) -> bucket bases
__global__ __launch_bounds__(1024) void k_bscan(
    const int* __restrict__ gcur, int* __restrict__ bbase) {
    __shared__ int s[1024];
    int tid = threadIdx.x;
    int v = (tid < NB) ? gcur[tid] : 0;
    s[tid] = v;
    __syncthreads();
    for (int off = 1; off < 1024; off <<= 1) {
        int t = s[tid];
        if (tid >= off) t += s[tid - off];
        __syncthreads();
        s[tid] = t;
        __syncthreads();
    }
    if (tid < NB) bbase[tid] = s[tid] - v;
    if (tid == NB) bbase[NB] = NEDGES;
}

// fill pass 2a: per bucket, per-node degree in LDS -> dis + rowptr (coalesced)
__global__ __launch_bounds__(256) void k_fill2a(
    const int* __restrict__ bbase, const int* __restrict__ gcur,
    const int* __restrict__ tmp, float* __restrict__ dis,
    int* __restrict__ rowptr) {
    __shared__ int dcnt[128];
    __shared__ int sc[128];
    int b = blockIdx.x;
    int tid = threadIdx.x;
    int n0 = b << 7;
    int s0 = bbase[b];
    int n = gcur[b];
    const int* tb = tmp + b * BCAP;
    if (tid < 128) dcnt[tid] = 0;
    __syncthreads();
    for (int i = tid; i < n; i += 256)
        atomicAdd(&dcnt[tb[i] & 127], 1);
    __syncthreads();
    int node = n0 + tid;
    if (tid < 128) {
        int d = dcnt[tid];
        if (node < NNODES) dis[node] = d ? rsqrtf((float)d) : 0.0f;
        sc[tid] = d;
    }
    __syncthreads();
    for (int off = 1; off < 128; off <<= 1) {
        int t = 0;
        if (tid < 128) {
            t = sc[tid];
            if (tid >= off) t += sc[tid - off];
        }
        __syncthreads();
        if (tid < 128) sc[tid] = t;
        __syncthreads();
    }
    if (tid < 128 && node < NNODES) rowptr[node] = s0 + sc[tid] - dcnt[tid];
    if (b == 0 && tid == 0) rowptr[NNODES] = NEDGES;
}

// fill pass 2b: per bucket, order bucket edges into CSR layout in LDS,
// stream out src-only records coalesced.
__global__ __launch_bounds__(256) void k_fill2b(
    const int* __restrict__ bbase, const int* __restrict__ gcur,
    const int* __restrict__ rowptr, const int* __restrict__ tmp,
    int* __restrict__ cw) {
    __shared__ int seg[BCAP];
    __shared__ int cur[128];
    int b = blockIdx.x;
    int tid = threadIdx.x;
    int n0 = b << 7;
    int s0 = bbase[b];
    int n = gcur[b];
    const int* tb = tmp + b * BCAP;
    if (tid < 128) {
        int node = n0 + tid;
        cur[tid] = (node < NNODES) ? rowptr[node] - s0 : n;
    }
    __syncthreads();
    for (int i = tid; i < n; i += 256) {
        int t = tb[i];
        int ln = t & 127;
        int p = atomicAdd(&cur[ln], 1);
        if (p < BCAP) seg[p] = t >> 7;   // src
    }
    __syncthreads();
    for (int i = tid; i < n; i += 256) cw[s0 + i] = seg[i];
}

// one wave per node; 4 edge-groups x 16 lanes; each lane owns 4 dims (8 B fp16).
// weight dis[src] gathered per edge (L2-resident 400KB table, broadcast read).
// MODE 0/1: dst = x_next. MODE 2: fused out = ALPHA*(emb+x1+x2+y).
template <int MODE>
__global__ __launch_bounds__(256) void k_prop(
    const int* __restrict__ rowptr, const int* __restrict__ cw,
    const float* __restrict__ dis, const __half* __restrict__ xin,
    __half* __restrict__ dst, const __half* __restrict__ emb16,
    const __half* __restrict__ x1, const __half* __restrict__ x2) {
    int gt = blockIdx.x * 256 + threadIdx.x;
    int node = gt >> 6;
    if (node >= NNODES) return;
    int lane = threadIdx.x & 63;
    int g = lane >> 4;     // edge group 0..3
    int c = lane & 15;     // 4-dim chunk within row
    int r0 = __builtin_amdgcn_readfirstlane(rowptr[node]);
    int r1 = __builtin_amdgcn_readfirstlane(rowptr[node + 1]);
    float4 acc0 = {0.f, 0.f, 0.f, 0.f}, acc1 = {0.f, 0.f, 0.f, 0.f};
    float4 acc2 = {0.f, 0.f, 0.f, 0.f}, acc3 = {0.f, 0.f, 0.f, 0.f};
    int j = r0 + g;
    for (; j + 12 < r1; j += 16) {         // 4 edges per group in flight
        int s0 = cw[j], s1 = cw[j + 4], s2 = cw[j + 8], s3 = cw[j + 12];
        float w0 = dis[s0], w1 = dis[s1], w2 = dis[s2], w3 = dis[s3];
        float2 r0v = *(const float2*)(xin + (size_t)s0 * DIM + c * 4);
        float2 r1v = *(const float2*)(xin + (size_t)s1 * DIM + c * 4);
        float2 r2v = *(const float2*)(xin + (size_t)s2 * DIM + c * 4);
        float2 r3v = *(const float2*)(xin + (size_t)s3 * DIM + c * 4);
        float2 f0a = __half22float2(((__half2*)&r0v)[0]);
        float2 f0b = __half22float2(((__half2*)&r0v)[1]);
        float2 f1a = __half22float2(((__half2*)&r1v)[0]);
        float2 f1b = __half22float2(((__half2*)&r1v)[1]);
        float2 f2a = __half22float2(((__half2*)&r2v)[0]);
        float2 f2b = __half22float2(((__half2*)&r2v)[1]);
        float2 f3a = __half22float2(((__half2*)&r3v)[0]);
        float2 f3b = __half22float2(((__half2*)&r3v)[1]);
        acc0.x += w0 * f0a.x; acc0.y += w0 * f0a.y;
        acc0.z += w0 * f0b.x; acc0.w += w0 * f0b.y;
        acc1.x += w1 * f1a.x; acc1.y += w1 * f1a.y;
        acc1.z += w1 * f1b.x; acc1.w += w1 * f1b.y;
        acc2.x += w2 * f2a.x; acc2.y += w2 * f2a.y;
        acc2.z += w2 * f2b.x; acc2.w += w2 * f2b.y;
        acc3.x += w3 * f3a.x; acc3.y += w3 * f3a.y;
        acc3.z += w3 * f3b.x; acc3.w += w3 * f3b.y;
    }
    for (; j + 4 < r1; j += 8) {           // 2 edges
        int s0 = cw[j], s1 = cw[j + 4];
        float w0 = dis[s0], w1 = dis[s1];
        float2 r0v = *(const float2*)(xin + (size_t)s0 * DIM + c * 4);
        float2 r1v = *(const float2*)(xin + (size_t)s1 * DIM + c * 4);
        float2 f0a = __half22float2(((__half2*)&r0v)[0]);
        float2 f0b = __half22float2(((__half2*)&r0v)[1]);
        float2 f1a = __half22float2(((__half2*)&r1v)[0]);
        float2 f1b = __half22float2(((__half2*)&r1v)[1]);
        acc0.x += w0 * f0a.x; acc0.y += w0 * f0a.y;
        acc0.z += w0 * f0b.x; acc0.w += w0 * f0b.y;
        acc1.x += w1 * f1a.x; acc1.y += w1 * f1a.y;
        acc1.z += w1 * f1b.x; acc1.w += w1 * f1b.y;
    }
    for (; j < r1; j += 4) {               // 1 edge
        int s = cw[j];
        float w = dis[s];
        float2 rv = *(const float2*)(xin + (size_t)s * DIM + c * 4);
        float2 f0 = __half22float2(((__half2*)&rv)[0]);
        float2 f1 = __half22float2(((__half2*)&rv)[1]);
        acc0.x += w * f0.x; acc0.y += w * f0.y;
        acc0.z += w * f1.x; acc0.w += w * f1.y;
    }
    acc0.x += acc1.x; acc0.y += acc1.y; acc0.z += acc1.z; acc0.w += acc1.w;
    acc2.x += acc3.x; acc2.y += acc3.y; acc2.z += acc3.z; acc2.w += acc3.w;
    acc0.x += acc2.x; acc0.y += acc2.y; acc0.z += acc2.z; acc0.w += acc2.w;
    acc0.x += __shfl_xor(acc0.x, 16); acc0.y += __shfl_xor(acc0.y, 16);
    acc0.z += __shfl_xor(acc0.z, 16); acc0.w += __shfl_xor(acc0.w, 16);
    acc0.x += __shfl_xor(acc0.x, 32); acc0.y += __shfl_xor(acc0.y, 32);
    acc0.z += __shfl_xor(acc0.z, 32); acc0.w += __shfl_xor(acc0.w, 32);
    if (lane < 16) {
        float dn = dis[node];
        float yx = dn * acc0.x, yy = dn * acc0.y;
        float yz = dn * acc0.z, yw = dn * acc0.w;
        size_t idx = (size_t)node * DIM + c * 4;
        if (MODE == 2) {
            float2 eb = *(const float2*)(emb16 + idx);
            float2 ab = *(const float2*)(x1 + idx);
            float2 bb = *(const float2*)(x2 + idx);
            float2 e0 = __half22float2(((__half2*)&eb)[0]);
            float2 e1 = __half22float2(((__half2*)&eb)[1]);
            float2 a0 = __half22float2(((__half2*)&ab)[0]);
            float2 a1 = __half22float2(((__half2*)&ab)[1]);
            float2 b0 = __half22float2(((__half2*)&bb)[0]);
            float2 b1 = __half22float2(((__half2*)&bb)[1]);
            yx = ALPHA * (e0.x + a0.x + b0.x + yx);
            yy = ALPHA * (e0.y + a0.y + b0.y + yy);
            yz = ALPHA * (e1.x + a1.x + b1.x + yz);
            yw = ALPHA * (e1.y + a1.y + b1.y + yw);
        }
        float2 bits;
        ((__half2*)&bits)[0] = __float22half2_rn(make_float2(yx, yy));
        ((__half2*)&bits)[1] = __float22half2_rn(make_float2(yz, yw));
        *(float2*)(dst + idx) = bits;
    }
}

// LDS-tiled MLP GEMM over fp16 outf: 64 labels/block, xs k-major fp32 in LDS.
__global__ __launch_bounds__(256) void k_mlp(
    const __half* __restrict__ outf, const int* __restrict__ eli,
    const float* __restrict__ lbl, const float* __restrict__ W1,
    const float* __restrict__ b1, const float* __restrict__ W2,
    const float* __restrict__ b2, float* __restrict__ pred,
    float* __restrict__ partial) {
    __shared__ float xs[128][68];
    __shared__ float w1s[128 * 64];
    __shared__ float ws[4];
    int tid = threadIdx.x;
    int lb = blockIdx.x * 64;

    {
        const float4* src = (const float4*)W1;
        float4* dst = (float4*)w1s;
        for (int i = tid; i < 2048; i += 256) dst[i] = src[i];
    }
    {
        int lab = tid >> 2, q = tid & 3;
        int l = lb + lab;
        int li = (l < NLABEL) ? l : (NLABEL - 1);
        int s = eli[li];
        int t = eli[NLABEL + li];
        const __half* srow = outf + (size_t)s * DIM;
        const __half* trow = outf + (size_t)t * DIM;
#pragma unroll
        for (int i = 0; i < 4; ++i) {
            int cc = q + 4 * i;           // 16B chunk 0..15 of the 256B concat row
            const __half* row = (cc < 8) ? srow + cc * 8 : trow + (cc - 8) * 8;
            float4 raw = *(const float4*)row;   // 8 halfs
            __half2* hp = (__half2*)&raw;
            int k = 8 * cc;
            float2 f;
            f = __half22float2(hp[0]); xs[k + 0][lab] = f.x; xs[k + 1][lab] = f.y;
            f = __half22float2(hp[1]); xs[k + 2][lab] = f.x; xs[k + 3][lab] = f.y;
            f = __half22float2(hp[2]); xs[k + 4][lab] = f.x; xs[k + 5][lab] = f.y;
            f = __half22float2(hp[3]); xs[k + 6][lab] = f.x; xs[k + 7][lab] = f.y;
        }
    }
    __syncthreads();

    int jcol = tid & 15;
    int lrow = tid >> 4;
    float acc[4][4];
#pragma unroll
    for (int a = 0; a < 4; ++a)
#pragma unroll
        for (int b = 0; b < 4; ++b) acc[a][b] = 0.f;

#pragma unroll 4
    for (int k = 0; k < 128; ++k) {
        float4 xv = *(const float4*)(&xs[k][4 * lrow]);
        float4 wv = *(const float4*)(&w1s[k * 64 + 4 * jcol]);
        acc[0][0] += xv.x * wv.x; acc[0][1] += xv.x * wv.y;
        acc[0][2] += xv.x * wv.z; acc[0][3] += xv.x * wv.w;
        acc[1][0] += xv.y * wv.x; acc[1][1] += xv.y * wv.y;
        acc[1][2] += xv.y * wv.z; acc[1][3] += xv.y * wv.w;
        acc[2][0] += xv.z * wv.x; acc[2][1] += xv.z * wv.y;
        acc[2][2] += xv.z * wv.z; acc[2][3] += xv.z * wv.w;
        acc[3][0] += xv.w * wv.x; acc[3][1] += xv.w * wv.y;
        acc[3][2] += xv.w * wv.z; acc[3][3] += xv.w * wv.w;
    }

    float4 b1v = *(const float4*)(b1 + 4 * jcol);
    float4 w2v = *(const float4*)(W2 + 4 * jcol);
    float p[4];
#pragma unroll
    for (int a = 0; a < 4; ++a) {
        p[a] = fmaxf(acc[a][0] + b1v.x, 0.f) * w2v.x
             + fmaxf(acc[a][1] + b1v.y, 0.f) * w2v.y
             + fmaxf(acc[a][2] + b1v.z, 0.f) * w2v.z
             + fmaxf(acc[a][3] + b1v.w, 0.f) * w2v.w;
    }
#pragma unroll
    for (int off = 1; off <= 8; off <<= 1) {
#pragma unroll
        for (int a = 0; a < 4; ++a) p[a] += __shfl_xor(p[a], off);
    }
    float lsum = 0.f;
    if (jcol == 0) {
        float b2v = b2[0];
#pragma unroll
        for (int a = 0; a < 4; ++a) {
            int l = lb + 4 * lrow + a;
            if (l < NLABEL) {
                float predv = p[a] + b2v;
                pred[l] = predv;
                float d = predv - lbl[l];
                lsum += d * d;
            }
        }
    }
    lsum += __shfl_xor(lsum, 16);
    lsum += __shfl_xor(lsum, 32);
    if ((tid & 63) == 0) ws[tid >> 6] = lsum;
    __syncthreads();
    if (tid == 0) partial[blockIdx.x] = (ws[0] + ws[1]) + (ws[2] + ws[3]);
}

__global__ void k_loss(const float* __restrict__ partial, float* __restrict__ lossout,
                       int n) {
    __shared__ float s[512];
    int tid = threadIdx.x;
    float v = 0.f;
    for (int i = tid; i < n; i += 512) v += partial[i];
    s[tid] = v;
    __syncthreads();
    for (int off = 256; off >= 1; off >>= 1) {
        if (tid < off) s[tid] += s[tid + off];
        __syncthreads();
    }
    if (tid == 0) lossout[0] = s[0] / (float)NLABEL;
}

extern "C" void kernel_launch(void* const* d_in, const int* in_sizes, int n_in,
                              void* d_out, int out_size, void* d_ws, size_t ws_size,
                              hipStream_t stream) {
    const int*   ei  = (const int*)d_in[0];
    const int*   eli = (const int*)d_in[1];
    const float* lbl = (const float*)d_in[2];
    const float* emb = (const float*)d_in[3];
    const float* W1  = (const float*)d_in[4];
    const float* b1  = (const float*)d_in[5];
    const float* W2  = (const float*)d_in[6];
    const float* b2  = (const float*)d_in[7];
    float* outp = (float*)d_out;               // pred[100000] ++ loss[1]

    char* wsb = (char*)d_ws;
    float*  dis    = (float*)wsb + OFF_DIS;
    int*    rowptr = (int*)wsb + OFF_ROWPTR;
    int*    bbase  = (int*)wsb + OFF_BBASE;
    int*    gcur   = (int*)wsb + OFF_GCUR;
    int*    cw     = (int*)wsb + OFF_CW;
    __half* emb16  = (__half*)((int*)wsb + OFF_EMB16);
    __half* x1     = (__half*)((int*)wsb + OFF_X1);
    __half* x2     = (__half*)((int*)wsb + OFF_X2);
    __half* outf   = (__half*)((int*)wsb + OFF_OUTF16);
    float*  part   = (float*)wsb + OFF_PART;
    int*    tmp    = (int*)wsb + OFF_X1;       // alias: dead before k_prop<0>

    const int T = 256;
    hipMemsetAsync(gcur, 0, NB * sizeof(int), stream);
    hipLaunchKernelGGL(k_cvt, dim3((NNODES * DIM / 4 + T - 1) / T), dim3(T), 0, stream, emb, emb16);
    hipLaunchKernelGGL(k_fill1, dim3(NBLKF), dim3(1024), 0, stream, ei, gcur, tmp);
    hipLaunchKernelGGL(k_bscan, dim3(1), dim3(1024), 0, stream, gcur, bbase);
    hipLaunchKernelGGL(k_fill2a, dim3(NB), dim3(T), 0, stream, bbase, gcur, tmp, dis, rowptr);
    hipLaunchKernelGGL(k_fill2b, dim3(NB), dim3(T), 0, stream, bbase, gcur, rowptr, tmp, cw);

    // x1 = P(emb); x2 = P(x1); outf = ALPHA*(emb + x1 + x2 + P(x2))   [all fp16]
    dim3 pgrid((NNODES * 64) / T);
    hipLaunchKernelGGL((k_prop<0>), pgrid, dim3(T), 0, stream, rowptr, cw, dis, emb16, x1,   nullptr, nullptr, nullptr);
    hipLaunchKernelGGL((k_prop<1>), pgrid, dim3(T), 0, stream, rowptr, cw, dis, x1,    x2,   nullptr, nullptr, nullptr);
    hipLaunchKernelGGL((k_prop<2>), pgrid, dim3(T), 0, stream, rowptr, cw, dis, x2,    outf, emb16, x1, x2);

    const int MLPB = (NLABEL + 63) / 64;   // 1563
    hipLaunchKernelGGL(k_mlp, dim3(MLPB), dim3(T), 0, stream, outf, eli, lbl, W1, b1, W2, b2, outp, part);
    hipLaunchKernelGGL(k_loss, dim3(1), dim3(512), 0, stream, part, outp + NLABEL, MLPB);
}

// Round 10
// 200.759 us; speedup vs baseline: 1.4434x; 1.1189x over previous
//
#include <hip/hip_runtime.h>
#include <hip/hip_fp16.h>
#include <math.h>

// ---- problem constants (match reference) ----
#define NNODES 100000
#define NEDGES 1600000
#define NLABEL 100000
#define DIM    64
#define ALPHA  0.25f            // 1/(NUM_LAYERS+1)
#define NB     782               // coarse buckets of 128 nodes (dst >> 7)
#define NBLKF  256               // blocks for fill1 (1024 threads each)
#define BCAP   4096              // per-bucket tmp capacity (mean 2046, sigma 45)
#define XS_LD  136               // padded LDS row stride (halfs) for MFMA tiles

typedef _Float16 half8 __attribute__((ext_vector_type(8)));
typedef float    f32x4 __attribute__((ext_vector_type(4)));

// ---- workspace layout (u32 words) ----
constexpr size_t OFF_DIS    = 0;         // f32 [100096]
constexpr size_t OFF_ROWPTR = 100096;    // int [100001] (pad to 200192)
constexpr size_t OFF_BBASE  = 200192;    // int [NB+1]
constexpr size_t OFF_GCUR   = 201088;    // int [NB]
constexpr size_t OFF_CW     = 202880;    // int [1600000] (src only)
constexpr size_t OFF_EMB16  = 3402880;   // half[6400000] = 3200000 words
constexpr size_t OFF_X1     = 6602880;   // half[6400000] (aliased by tmp during fill)
constexpr size_t OFF_X2     = 9802880;   // half[6400000]
constexpr size_t OFF_OUTF16 = 13002880;  // half[6400000]
constexpr size_t OFF_PART   = 16202880;  // f32 [2048]
constexpr size_t OFF_W1T    = 16204928;  // half[8192] = 4096 words (W1 transposed)

// convert fp32 embedding -> fp16; extra block (bid==6250): zero gcur + build W1T
__global__ void k_cvt(const float* __restrict__ emb, __half* __restrict__ emb16,
                      const float* __restrict__ W1, __half* __restrict__ w1t,
                      int* __restrict__ gcur) {
    int bid = blockIdx.x;
    int tid = threadIdx.x;
    if (bid < 6250) {
        int i = bid * 256 + tid;             // one float4 / thread, exactly 1.6M
        float4 v = ((const float4*)emb)[i];
        float2 bits;
        ((__half2*)&bits)[0] = __float22half2_rn(make_float2(v.x, v.y));
        ((__half2*)&bits)[1] = __float22half2_rn(make_float2(v.z, v.w));
        ((float2*)emb16)[i] = bits;
    } else {
        for (int i = tid; i < NB; i += 256) gcur[i] = 0;
        for (int idx = tid; idx < 8192; idx += 256) {
            int j = idx & 63;                // hidden col
            int k = idx >> 6;                // k index
            w1t[j * 128 + k] = __float2half_rn(W1[k * 64 + j]);
        }
    }
}

// single-pass binning: per-block LDS hist -> one global reserve per bucket ->
// packed 4B records (src<<7 | dst&127) into fixed-capacity bucket regions.
__global__ __launch_bounds__(1024) void k_fill1(
    const int* __restrict__ ei, int* __restrict__ gcur,
    int* __restrict__ tmp) {
    __shared__ int hist[NB];
    __shared__ int base[NB];
    int tid = threadIdx.x;
    const int chunk = (((NEDGES + NBLKF - 1) / NBLKF) + 3) & ~3;   // 6252 (x4)
    int e0 = blockIdx.x * chunk;
    int e1 = min(e0 + chunk, NEDGES);
    for (int i = tid; i < NB; i += 1024) hist[i] = 0;
    __syncthreads();
    const int* srcs = ei;
    const int* dsts = ei + NEDGES;
    for (int e = e0 + tid * 4; e + 3 < e1; e += 4096) {
        int4 d = *(const int4*)(dsts + e);
        atomicAdd(&hist[d.x >> 7], 1);
        atomicAdd(&hist[d.y >> 7], 1);
        atomicAdd(&hist[d.z >> 7], 1);
        atomicAdd(&hist[d.w >> 7], 1);
    }
    __syncthreads();
    for (int b = tid; b < NB; b += 1024) {
        int c = hist[b];
        base[b] = c ? atomicAdd(&gcur[b], c) : 0;
        hist[b] = 0;
    }
    __syncthreads();
    for (int e = e0 + tid * 4; e + 3 < e1; e += 4096) {
        int4 s = *(const int4*)(srcs + e);
        int4 d = *(const int4*)(dsts + e);
        int b0 = d.x >> 7, b1 = d.y >> 7, b2 = d.z >> 7, b3 = d.w >> 7;
        int l0 = atomicAdd(&hist[b0], 1);
        int l1 = atomicAdd(&hist[b1], 1);
        int l2 = atomicAdd(&hist[b2], 1);
        int l3 = atomicAdd(&hist[b3], 1);
        int p0 = b0 * BCAP + min(base[b0] + l0, BCAP - 1);
        int p1 = b1 * BCAP + min(base[b1] + l1, BCAP - 1);
        int p2 = b2 * BCAP + min(base[b2] + l2, BCAP - 1);
        int p3 = b3 * BCAP + min(base[b3] + l3, BCAP - 1);
        tmp[p0] = (s.x << 7) | (d.x & 127);
        tmp[p1] = (s.y << 7) | (d.y & 127);
        tmp[p2] = (s.z << 7) | (d.z & 127);
        tmp[p3] = (s.w << 7) | (d.w & 127);
    }
}

// exclusive scan of bucket counts (in gcur) -> bucket bases
__global__ __launch_bounds__(1024) void k_bscan(
    const int* __restrict__ gcur, int* __restrict__ bbase) {
    __shared__ int s[1024];
    int tid = threadIdx.x;
    int v = (tid < NB) ? gcur[tid] : 0;
    s[tid] = v;
    __syncthreads();
    for (int off = 1; off < 1024; off <<= 1) {
        int t = s[tid];
        if (tid >= off) t += s[tid - off];
        __syncthreads();
        s[tid] = t;
        __syncthreads();
    }
    if (tid < NB) bbase[tid] = s[tid] - v;
    if (tid == NB) bbase[NB] = NEDGES;
}

// merged fill pass 2: per bucket — read tmp once into LDS, per-node degree,
// dis + rowptr, CSR reorder in LDS, coalesced stream-out of src records.
__global__ __launch_bounds__(256) void k_fill2(
    const int* __restrict__ bbase, const int* __restrict__ gcur,
    const int* __restrict__ tmp, float* __restrict__ dis,
    int* __restrict__ rowptr, int* __restrict__ cw) {
    __shared__ int raw[BCAP];
    __shared__ int seg[BCAP];
    __shared__ int dcnt[128];
    __shared__ int sc[128];
    __shared__ int cur[128];
    int b = blockIdx.x;
    int tid = threadIdx.x;
    int n0 = b << 7;
    int s0 = bbase[b];
    int n = gcur[b];
    const int* tb = tmp + b * BCAP;
    if (tid < 128) dcnt[tid] = 0;
    __syncthreads();
    for (int i = tid; i < n; i += 256) {
        int t = tb[i];
        raw[i] = t;
        atomicAdd(&dcnt[t & 127], 1);
    }
    __syncthreads();
    int node = n0 + tid;
    if (tid < 128) {
        int d = dcnt[tid];
        if (node < NNODES) dis[node] = d ? rsqrtf((float)d) : 0.0f;
        sc[tid] = d;
    }
    __syncthreads();
    for (int off = 1; off < 128; off <<= 1) {
        int t = 0;
        if (tid < 128) {
            t = sc[tid];
            if (tid >= off) t += sc[tid - off];
        }
        __syncthreads();
        if (tid < 128) sc[tid] = t;
        __syncthreads();
    }
    if (tid < 128) {
        int excl = sc[tid] - dcnt[tid];
        if (node < NNODES) rowptr[node] = s0 + excl;
        cur[tid] = excl;
    }
    if (b == 0 && tid == 0) rowptr[NNODES] = NEDGES;
    __syncthreads();
    for (int i = tid; i < n; i += 256) {
        int t = raw[i];
        int p = atomicAdd(&cur[t & 127], 1);
        if (p < BCAP) seg[p] = t >> 7;   // src
    }
    __syncthreads();
    for (int i = tid; i < n; i += 256) cw[s0 + i] = seg[i];
}

// one wave per node; 4 edge-groups x 16 lanes; each lane owns 4 dims (8 B fp16).
// MODE 0/1: dst = x_next. MODE 2: fused out = ALPHA*(emb+x1+x2+y).
template <int MODE>
__global__ __launch_bounds__(256) void k_prop(
    const int* __restrict__ rowptr, const int* __restrict__ cw,
    const float* __restrict__ dis, const __half* __restrict__ xin,
    __half* __restrict__ dst, const __half* __restrict__ emb16,
    const __half* __restrict__ x1, const __half* __restrict__ x2) {
    int gt = blockIdx.x * 256 + threadIdx.x;
    int node = gt >> 6;
    if (node >= NNODES) return;
    int lane = threadIdx.x & 63;
    int g = lane >> 4;     // edge group 0..3
    int c = lane & 15;     // 4-dim chunk within row
    int r0 = __builtin_amdgcn_readfirstlane(rowptr[node]);
    int r1 = __builtin_amdgcn_readfirstlane(rowptr[node + 1]);
    float4 acc0 = {0.f, 0.f, 0.f, 0.f}, acc1 = {0.f, 0.f, 0.f, 0.f};
    float4 acc2 = {0.f, 0.f, 0.f, 0.f}, acc3 = {0.f, 0.f, 0.f, 0.f};
    int j = r0 + g;
    for (; j + 12 < r1; j += 16) {         // 4 edges per group in flight
        int s0 = cw[j], s1 = cw[j + 4], s2 = cw[j + 8], s3 = cw[j + 12];
        float w0 = dis[s0], w1 = dis[s1], w2 = dis[s2], w3 = dis[s3];
        float2 r0v = *(const float2*)(xin + (size_t)s0 * DIM + c * 4);
        float2 r1v = *(const float2*)(xin + (size_t)s1 * DIM + c * 4);
        float2 r2v = *(const float2*)(xin + (size_t)s2 * DIM + c * 4);
        float2 r3v = *(const float2*)(xin + (size_t)s3 * DIM + c * 4);
        float2 f0a = __half22float2(((__half2*)&r0v)[0]);
        float2 f0b = __half22float2(((__half2*)&r0v)[1]);
        float2 f1a = __half22float2(((__half2*)&r1v)[0]);
        float2 f1b = __half22float2(((__half2*)&r1v)[1]);
        float2 f2a = __half22float2(((__half2*)&r2v)[0]);
        float2 f2b = __half22float2(((__half2*)&r2v)[1]);
        float2 f3a = __half22float2(((__half2*)&r3v)[0]);
        float2 f3b = __half22float2(((__half2*)&r3v)[1]);
        acc0.x += w0 * f0a.x; acc0.y += w0 * f0a.y;
        acc0.z += w0 * f0b.x; acc0.w += w0 * f0b.y;
        acc1.x += w1 * f1a.x; acc1.y += w1 * f1a.y;
        acc1.z += w1 * f1b.x; acc1.w += w1 * f1b.y;
        acc2.x += w2 * f2a.x; acc2.y += w2 * f2a.y;
        acc2.z += w2 * f2b.x; acc2.w += w2 * f2b.y;
        acc3.x += w3 * f3a.x; acc3.y += w3 * f3a.y;
        acc3.z += w3 * f3b.x; acc3.w += w3 * f3b.y;
    }
    for (; j + 4 < r1; j += 8) {           // 2 edges
        int s0 = cw[j], s1 = cw[j + 4];
        float w0 = dis[s0], w1 = dis[s1];
        float2 r0v = *(const float2*)(xin + (size_t)s0 * DIM + c * 4);
        float2 r1v = *(const float2*)(xin + (size_t)s1 * DIM + c * 4);
        float2 f0a = __half22float2(((__half2*)&r0v)[0]);
        float2 f0b = __half22float2(((__half2*)&r0v)[1]);
        float2 f1a = __half22float2(((__half2*)&r1v)[0]);
        float2 f1b = __half22float2(((__half2*)&r1v)[1]);
        acc0.x += w0 * f0a.x; acc0.y += w0 * f0a.y;
        acc0.z += w0 * f0b.x; acc0.w += w0 * f0b.y;
        acc1.x += w1 * f1a.x; acc1.y += w1 * f1a.y;
        acc1.z += w1 * f1b.x; acc1.w += w1 * f1b.y;
    }
    for (; j < r1; j += 4) {               // 1 edge
        int s = cw[j];
        float w = dis[s];
        float2 rv = *(const float2*)(xin + (size_t)s * DIM + c * 4);
        float2 f0 = __half22float2(((__half2*)&rv)[0]);
        float2 f1 = __half22float2(((__half2*)&rv)[1]);
        acc0.x += w * f0.x; acc0.y += w * f0.y;
        acc0.z += w * f1.x; acc0.w += w * f1.y;
    }
    acc0.x += acc1.x; acc0.y += acc1.y; acc0.z += acc1.z; acc0.w += acc1.w;
    acc2.x += acc3.x; acc2.y += acc3.y; acc2.z += acc3.z; acc2.w += acc3.w;
    acc0.x += acc2.x; acc0.y += acc2.y; acc0.z += acc2.z; acc0.w += acc2.w;
    acc0.x += __shfl_xor(acc0.x, 16); acc0.y += __shfl_xor(acc0.y, 16);
    acc0.z += __shfl_xor(acc0.z, 16); acc0.w += __shfl_xor(acc0.w, 16);
    acc0.x += __shfl_xor(acc0.x, 32); acc0.y += __shfl_xor(acc0.y, 32);
    acc0.z += __shfl_xor(acc0.z, 32); acc0.w += __shfl_xor(acc0.w, 32);
    if (lane < 16) {
        float dn = dis[node];
        float yx = dn * acc0.x, yy = dn * acc0.y;
        float yz = dn * acc0.z, yw = dn * acc0.w;
        size_t idx = (size_t)node * DIM + c * 4;
        if (MODE == 2) {
            float2 eb = *(const float2*)(emb16 + idx);
            float2 ab = *(const float2*)(x1 + idx);
            float2 bb = *(const float2*)(x2 + idx);
            float2 e0 = __half22float2(((__half2*)&eb)[0]);
            float2 e1 = __half22float2(((__half2*)&eb)[1]);
            float2 a0 = __half22float2(((__half2*)&ab)[0]);
            float2 a1 = __half22float2(((__half2*)&ab)[1]);
            float2 b0 = __half22float2(((__half2*)&bb)[0]);
            float2 b1 = __half22float2(((__half2*)&bb)[1]);
            yx = ALPHA * (e0.x + a0.x + b0.x + yx);
            yy = ALPHA * (e0.y + a0.y + b0.y + yy);
            yz = ALPHA * (e1.x + a1.x + b1.x + yz);
            yw = ALPHA * (e1.y + a1.y + b1.y + yw);
        }
        float2 bits;
        ((__half2*)&bits)[0] = __float22half2_rn(make_float2(yx, yy));
        ((__half2*)&bits)[1] = __float22half2_rn(make_float2(yz, yw));
        *(float2*)(dst + idx) = bits;
    }
}

// MFMA MLP: 64 labels/block, 4 waves = 4 M-tiles of 16 labels.
// X[64][128] fp16 and W1T[64][128] fp16 staged in LDS (stride 136 halfs).
// D = X @ W1 via mfma_f32_16x16x32_f16; epilogue relu+W2 dot in registers.
__global__ __launch_bounds__(256) void k_mlp(
    const __half* __restrict__ outf, const int* __restrict__ eli,
    const float* __restrict__ lbl, const __half* __restrict__ w1t,
    const float* __restrict__ b1, const float* __restrict__ W2,
    const float* __restrict__ b2, float* __restrict__ pred,
    float* __restrict__ partial) {
    __shared__ _Float16 xs[64 * XS_LD];
    __shared__ _Float16 ws1[64 * XS_LD];
    __shared__ float wsum[4];
    int tid = threadIdx.x;
    int lb = blockIdx.x * 64;

    // stage W1T (64 rows x 16 chunks of 8 halfs)
    for (int idx = tid; idx < 1024; idx += 256) {
        int row = idx >> 4, ch = idx & 15;
        *(float4*)&ws1[row * XS_LD + ch * 8] = ((const float4*)w1t)[idx];
    }
    // gather 64 labels' concat rows into xs (fp16, [label][k])
    {
        int lab = tid >> 2, q = tid & 3;
        int l = lb + lab;
        int li = (l < NLABEL) ? l : (NLABEL - 1);
        int s = eli[li];
        int t = eli[NLABEL + li];
        const __half* srow = outf + (size_t)s * DIM;
        const __half* trow = outf + (size_t)t * DIM;
#pragma unroll
        for (int i = 0; i < 4; ++i) {
            int cc = q + 4 * i;           // chunk 0..15 (8 halfs each)
            const __half* row = (cc < 8) ? srow + cc * 8 : trow + (cc - 8) * 8;
            *(float4*)&xs[lab * XS_LD + cc * 8] = *(const float4*)row;
        }
    }
    __syncthreads();

    int wid = tid >> 6;          // M-tile
    int lane = tid & 63;
    int lrow = lane & 15;        // A row / B col / D col
    int kgrp = lane >> 4;        // k-group
    f32x4 acc[4];
#pragma unroll
    for (int nt = 0; nt < 4; ++nt) acc[nt] = (f32x4){0.f, 0.f, 0.f, 0.f};

#pragma unroll
    for (int ks = 0; ks < 4; ++ks) {
        half8 a = *(const half8*)&xs[(wid * 16 + lrow) * XS_LD + ks * 32 + kgrp * 8];
#pragma unroll
        for (int nt = 0; nt < 4; ++nt) {
            half8 b = *(const half8*)&ws1[(nt * 16 + lrow) * XS_LD + ks * 32 + kgrp * 8];
            acc[nt] = __builtin_amdgcn_mfma_f32_16x16x32_f16(a, b, acc[nt], 0, 0, 0);
        }
    }

    // epilogue: h = relu(acc + b1), p = h . W2 ; D col = lane&15, row = kgrp*4+reg
    float p[4] = {0.f, 0.f, 0.f, 0.f};
#pragma unroll
    for (int nt = 0; nt < 4; ++nt) {
        float b1v = b1[nt * 16 + lrow];
        float w2v = W2[nt * 16 + lrow];
#pragma unroll
        for (int r = 0; r < 4; ++r)
            p[r] += fmaxf(acc[nt][r] + b1v, 0.f) * w2v;
    }
#pragma unroll
    for (int off = 1; off <= 8; off <<= 1) {
#pragma unroll
        for (int r = 0; r < 4; ++r) p[r] += __shfl_xor(p[r], off);
    }
    float lsum = 0.f;
    if (lrow == 0) {
        float b2v = b2[0];
#pragma unroll
        for (int r = 0; r < 4; ++r) {
            int l = lb + wid * 16 + kgrp * 4 + r;
            if (l < NLABEL) {
                float predv = p[r] + b2v;
                pred[l] = predv;
                float d = predv - lbl[l];
                lsum += d * d;
            }
        }
    }
    lsum += __shfl_xor(lsum, 16);
    lsum += __shfl_xor(lsum, 32);
    if (lane == 0) wsum[wid] = lsum;
    __syncthreads();
    if (tid == 0) partial[blockIdx.x] = (wsum[0] + wsum[1]) + (wsum[2] + wsum[3]);
}

__global__ void k_loss(const float* __restrict__ partial, float* __restrict__ lossout,
                       int n) {
    __shared__ float s[512];
    int tid = threadIdx.x;
    float v = 0.f;
    for (int i = tid; i < n; i += 512) v += partial[i];
    s[tid] = v;
    __syncthreads();
    for (int off = 256; off >= 1; off >>= 1) {
        if (tid < off) s[tid] += s[tid + off];
        __syncthreads();
    }
    if (tid == 0) lossout[0] = s[0] / (float)NLABEL;
}

extern "C" void kernel_launch(void* const* d_in, const int* in_sizes, int n_in,
                              void* d_out, int out_size, void* d_ws, size_t ws_size,
                              hipStream_t stream) {
    const int*   ei  = (const int*)d_in[0];
    const int*   eli = (const int*)d_in[1];
    const float* lbl = (const float*)d_in[2];
    const float* emb = (const float*)d_in[3];
    const float* W1  = (const float*)d_in[4];
    const float* b1  = (const float*)d_in[5];
    const float* W2  = (const float*)d_in[6];
    const float* b2  = (const float*)d_in[7];
    float* outp = (float*)d_out;               // pred[100000] ++ loss[1]

    char* wsb = (char*)d_ws;
    float*  dis    = (float*)wsb + OFF_DIS;
    int*    rowptr = (int*)wsb + OFF_ROWPTR;
    int*    bbase  = (int*)wsb + OFF_BBASE;
    int*    gcur   = (int*)wsb + OFF_GCUR;
    int*    cw     = (int*)wsb + OFF_CW;
    __half* emb16  = (__half*)((int*)wsb + OFF_EMB16);
    __half* x1     = (__half*)((int*)wsb + OFF_X1);
    __half* x2     = (__half*)((int*)wsb + OFF_X2);
    __half* outf   = (__half*)((int*)wsb + OFF_OUTF16);
    float*  part   = (float*)wsb + OFF_PART;
    __half* w1t    = (__half*)((int*)wsb + OFF_W1T);
    int*    tmp    = (int*)wsb + OFF_X1;       // alias: dead before k_prop<0>

    const int T = 256;
    hipLaunchKernelGGL(k_cvt, dim3(6251), dim3(T), 0, stream, emb, emb16, W1, w1t, gcur);
    hipLaunchKernelGGL(k_fill1, dim3(NBLKF), dim3(1024), 0, stream, ei, gcur, tmp);
    hipLaunchKernelGGL(k_bscan, dim3(1), dim3(1024), 0, stream, gcur, bbase);
    hipLaunchKernelGGL(k_fill2, dim3(NB), dim3(T), 0, stream, bbase, gcur, tmp, dis, rowptr, cw);

    // x1 = P(emb); x2 = P(x1); outf = ALPHA*(emb + x1 + x2 + P(x2))   [all fp16]
    dim3 pgrid((NNODES * 64) / T);
    hipLaunchKernelGGL((k_prop<0>), pgrid, dim3(T), 0, stream, rowptr, cw, dis, emb16, x1,   nullptr, nullptr, nullptr);
    hipLaunchKernelGGL((k_prop<1>), pgrid, dim3(T), 0, stream, rowptr, cw, dis, x1,    x2,   nullptr, nullptr, nullptr);
    hipLaunchKernelGGL((k_prop<2>), pgrid, dim3(T), 0, stream, rowptr, cw, dis, x2,    outf, emb16, x1, x2);

    const int MLPB = (NLABEL + 63) / 64;   // 1563
    hipLaunchKernelGGL(k_mlp, dim3(MLPB), dim3(T), 0, stream, outf, eli, lbl, w1t, b1, W2, b2, outp, part);
    hipLaunchKernelGGL(k_loss, dim3(1), dim3(512), 0, stream, part, outp + NLABEL, MLPB);
}